// Round 3
// baseline (2997.284 us; speedup 1.0000x reference)
//
#include <hip/hip_runtime.h>

#define T_ 4096
#define B_ 64
#define D_ 128
#define L_ 128

// ---------------------------------------------------------------------------
// Fully fused RNN: one WG per batch element (64 WGs x 256 threads = 4 waves).
// Thread (l = j>>1, half = j&1): owns output column l, k-half of both dots.
// Per step: pre[l] = x[t]*Wx[:,l] + h*Wh[:,l] + (bx+bh)[l]; h = tanh(pre).
// The x-projection is computed inline (no separate GEMM): x staged in LDS
// 8 steps per window, double-buffered, global loads issued 2 windows ahead
// so vmcnt waits are free. The x-dot FMAs are independent of h and fill the
// h-chain stall cycles (h LDS round-trip + tanh + barrier).
// Sync: raw s_barrier with lgkmcnt-only drain -> H-stores/x-loads stay in
// flight across steps (never drain vmcnt in-loop).
// ---------------------------------------------------------------------------
__global__ __launch_bounds__(256, 1) void rnn_fused(
    const float* __restrict__ x, const float* __restrict__ h0,
    const float* __restrict__ Wx, const float* __restrict__ bx,
    const float* __restrict__ Wh, const float* __restrict__ bh,
    float* __restrict__ out)
{
  __shared__ float hbuf[2][128];        // h ping-pong
  __shared__ float xtile[2][8][128];    // 8-step x window, double-buffered

  const int j = threadIdx.x;
  const int b = blockIdx.x;
  const int half = j & 1;
  const int l = j >> 1;                 // 0..127
  const int kb = half << 6;             // k base: 0 or 64

  // Column slices of the weights in VGPRs (one-time, coalesced: lanes of a
  // wave read consecutive l -> two 128B segments per instr).
  float wh[64], wx[64];
#pragma unroll
  for (int kk = 0; kk < 64; ++kk) {
    wh[kk] = Wh[(size_t)(kb + kk) * L_ + l];
    wx[kk] = Wx[(size_t)(kb + kk) * L_ + l];
  }
  const float bias = bh[l] + bx[l];     // fold both biases

  if (j < 128) hbuf[0][j] = h0[(size_t)b * L_ + j];

  // Stage x window 0 directly into LDS.
  {
    int r = j >> 5, c4 = (j & 31) * 4;
    float4 v = *reinterpret_cast<const float4*>(x + ((size_t)r * B_ + b) * D_ + c4);
    *reinterpret_cast<float4*>(&xtile[0][r][c4]) = v;
  }
  // Preload x window 1 into registers.
  float4 gx;
  {
    int r = 8 + (j >> 5), c4 = (j & 31) * 4;
    gx = *reinterpret_cast<const float4*>(x + ((size_t)r * B_ + b) * D_ + c4);
  }
  __syncthreads();

  const size_t ss = (size_t)B_ * L_;    // 8192 floats per timestep
  float* outp = out + (size_t)b * L_ + l;

  for (int t8 = 0; t8 < T_ / 8; ++t8) {
    const int cur = t8 & 1;
#pragma unroll
    for (int u = 0; u < 8; ++u) {
      const int pr = u & 1;             // h read-buffer parity (t8*8 is even)

      // --- window staging (amortized; waits are ~5 steps deep => free) ---
      if (u == 1) {                     // write window t8+1 (loaded last window)
        int r = j >> 5, c4 = (j & 31) * 4;
        *reinterpret_cast<float4*>(&xtile[cur ^ 1][r][c4]) = gx;
      }
      if (u == 4) {                     // issue loads for window t8+2
        int rr = (t8 + 2) * 8 + (j >> 5);
        if (rr > T_ - 1) rr = T_ - 1;   // clamped rows are never consumed
        int c4 = (j & 31) * 4;
        gx = *reinterpret_cast<const float4*>(x + ((size_t)rr * B_ + b) * D_ + c4);
      }

      // --- x-dot (independent of h: fills h-read latency) + h-dot ---
      const float* xr = &xtile[cur][u][kb];
      const float* hr = &hbuf[pr][kb];
      float a0 = 0.f, a1 = 0.f, a2 = 0.f, a3 = 0.f;
#pragma unroll
      for (int m = 0; m < 16; ++m) {
        float4 xv = *reinterpret_cast<const float4*>(xr + m * 4);
        a0 = fmaf(xv.x, wx[4 * m + 0], a0);
        a1 = fmaf(xv.y, wx[4 * m + 1], a1);
        a2 = fmaf(xv.z, wx[4 * m + 2], a2);
        a3 = fmaf(xv.w, wx[4 * m + 3], a3);
      }
#pragma unroll
      for (int m = 0; m < 16; ++m) {
        float4 hv = *reinterpret_cast<const float4*>(hr + m * 4);
        a0 = fmaf(hv.x, wh[4 * m + 0], a0);
        a1 = fmaf(hv.y, wh[4 * m + 1], a1);
        a2 = fmaf(hv.z, wh[4 * m + 2], a2);
        a3 = fmaf(hv.w, wh[4 * m + 3], a3);
      }
      float part = (a0 + a1) + (a2 + a3);
      float sum = part + __shfl_xor(part, 1, 64);  // pair reduce (DPP quad-perm)
      float pre = sum + bias;

      // tanh(pre): sign * (1-e)/(1+e), e = exp(-2|pre|)
      float aa = fabsf(pre);
      float e2 = __expf(-2.f * aa);
      float r1 = (1.f - e2) * __builtin_amdgcn_rcpf(1.f + e2);
      float hn = copysignf(r1, pre);

      if (half == 0) hbuf[pr ^ 1][l] = hn;  // even lane publishes h_{t+1}
      else           *outp = hn;            // odd lane stores H[t] (in flight)
      outp += ss;

      // LDS-only drain + raw barrier: vmcnt ops stay outstanding.
      asm volatile("s_waitcnt lgkmcnt(0)" ::: "memory");
      __builtin_amdgcn_s_barrier();
      __builtin_amdgcn_sched_barrier(0);
    }
  }
}

extern "C" void kernel_launch(void* const* d_in, const int* in_sizes, int n_in,
                              void* d_out, int out_size, void* d_ws, size_t ws_size,
                              hipStream_t stream) {
  const float* x  = (const float*)d_in[0];
  const float* h0 = (const float*)d_in[1];
  const float* Wx = (const float*)d_in[2];
  const float* bx = (const float*)d_in[3];
  const float* Wh = (const float*)d_in[4];
  const float* bh = (const float*)d_in[5];
  float* out = (float*)d_out;

  rnn_fused<<<B_, 256, 0, stream>>>(x, h0, Wx, bx, Wh, bh, out);
}

// Round 6
// 2560.565 us; speedup vs baseline: 1.1706x; 1.1706x over previous
//
#include <hip/hip_runtime.h>

#define T_ 4096
#define B_ 64
#define D_ 128
#define L_ 128

// DPP butterfly adds (pure VALU — __shfl_xor lowers to ds_bpermute, avoid).
// 0xB1 quad_perm [1,0,3,2] = xor1 ; 0x4E quad_perm [2,3,0,1] = xor2 ;
// 0x141 ROW_HALF_MIRROR (i -> 7-i within 8) == xor4 once quads are uniform.
template <int CTRL>
__device__ __forceinline__ float qp_add(float v) {
  int t = __builtin_amdgcn_update_dpp(0, __float_as_int(v), CTRL, 0xF, 0xF, true);
  return v + __int_as_float(t);
}

// ---------------------------------------------------------------------------
// Fused RNN v6. 64 WGs (1 batch / CU) x 512 threads (8 waves, 2/SIMD).
// Thread (lg = j>>3, kq = j&7): cols {2lg, 2lg+1}, k-slice [16kq, 16kq+16).
//  - h in LDS ping-pong; per-instruction rotated units put the 8 kq groups on
//    the 8 distinct bank quads (broadcast within group) -> 0 conflicts.
//  - C=2 halves h LDS return traffic vs one-col/thread (32 KB/step/CU).
//  - k-reduce: xor1+xor2+half-mirror, all DPP (no lgkm ops on the chain).
//  - x fused via per-thread global->register queue (depth 2): its 32 FMAs
//    fill the h ds_read latency; no LDS coupling.
//  - lgkmcnt-only drain + raw s_barrier per step: x-loads and H-stores stay
//    in flight across barriers (vmcnt never drained in-loop).
// ---------------------------------------------------------------------------
__global__ __launch_bounds__(512, 2) void rnn_fused4(
    const float* __restrict__ x, const float* __restrict__ h0,
    const float* __restrict__ Wx, const float* __restrict__ bx,
    const float* __restrict__ Wh, const float* __restrict__ bh,
    float* __restrict__ out)
{
  __shared__ float hbuf[2][128];

  const int j   = threadIdx.x;
  const int b   = blockIdx.x;
  const int lg  = j >> 3;                // 0..63
  const int kq  = j & 7;                 // k-group
  const int kb  = kq << 4;               // k base (16 floats)
  const int rot = kq >> 1;               // rotation seed
  const int c0  = 2 * lg, c1 = 2 * lg + 1;

  // Weights in VGPRs. wh in ROTATED unit order (matches ds_read schedule).
  float wh0[16], wh1[16], wx0[16], wx1[16];
#pragma unroll
  for (int m = 0; m < 4; ++m) {
    const int ku = (rot + m) & 3;        // slice-local float4 unit
#pragma unroll
    for (int e = 0; e < 4; ++e) {
      const int k = kb + 4 * ku + e;
      wh0[4 * m + e] = Wh[(size_t)k * L_ + c0];
      wh1[4 * m + e] = Wh[(size_t)k * L_ + c1];
    }
  }
#pragma unroll
  for (int i = 0; i < 16; ++i) {
    wx0[i] = Wx[(size_t)(kb + i) * L_ + c0];
    wx1[i] = Wx[(size_t)(kb + i) * L_ + c1];
  }
  const float bias0 = bx[c0] + bh[c0];
  const float bias1 = bx[c1] + bh[c1];

  if (j < 128) hbuf[0][j] = h0[(size_t)b * L_ + j];

  // x register queue, depth 2: slot t&1 holds x[t][b][kb..kb+16).
  float4 q[2][4];
#pragma unroll
  for (int u = 0; u < 2; ++u) {
    const float* p = x + ((size_t)u * B_ + b) * D_ + kb;
#pragma unroll
    for (int i = 0; i < 4; ++i)
      q[u][i] = *reinterpret_cast<const float4*>(p + 4 * i);
  }
  // Cursor at row t+2, advanced by uniform stride while t <= T-4 (clamp).
  const char* xp8 =
      reinterpret_cast<const char*>(x + ((size_t)2 * B_ + b) * D_ + kb);
  const size_t xstride = (size_t)B_ * D_ * sizeof(float);
  const int    obase   = b * L_ + c0;
  const size_t ss      = (size_t)B_ * L_;   // floats per timestep

  __syncthreads();

  for (int t4 = 0; t4 < T_ / 4; ++t4) {
#pragma unroll
    for (int u = 0; u < 4; ++u) {
      const int t  = 4 * t4 + u;
      const int pr = u & 1;              // == t&1 (h ping-pong parity)
      const int sl = u & 1;              // queue slot

      // x-dot (register-only; fills h ds_read latency).
      float ax0 = 0.f, ax1 = 0.f, bx0 = 0.f, bx1 = 0.f;
#pragma unroll
      for (int i = 0; i < 4; ++i) {
        const float4 xv = q[sl][i];
        ax0 = fmaf(xv.x, wx0[4 * i + 0], ax0);
        bx0 = fmaf(xv.y, wx0[4 * i + 1], bx0);
        ax0 = fmaf(xv.z, wx0[4 * i + 2], ax0);
        bx0 = fmaf(xv.w, wx0[4 * i + 3], bx0);
        ax1 = fmaf(xv.x, wx1[4 * i + 0], ax1);
        bx1 = fmaf(xv.y, wx1[4 * i + 1], bx1);
        ax1 = fmaf(xv.z, wx1[4 * i + 2], ax1);
        bx1 = fmaf(xv.w, wx1[4 * i + 3], bx1);
      }

      // h-dot: rotated units -> 8 kq groups on 8 distinct bank quads.
      float ah0 = 0.f, ah1 = 0.f, bh0 = 0.f, bh1 = 0.f;
      const float* hr = &hbuf[pr][kb];
#pragma unroll
      for (int m = 0; m < 4; ++m) {
        const int ku = (rot + m) & 3;
        const float4 hv = *reinterpret_cast<const float4*>(hr + 4 * ku);
        ah0 = fmaf(hv.x, wh0[4 * m + 0], ah0);
        bh0 = fmaf(hv.y, wh0[4 * m + 1], bh0);
        ah0 = fmaf(hv.z, wh0[4 * m + 2], ah0);
        bh0 = fmaf(hv.w, wh0[4 * m + 3], bh0);
        ah1 = fmaf(hv.x, wh1[4 * m + 0], ah1);
        bh1 = fmaf(hv.y, wh1[4 * m + 1], bh1);
        ah1 = fmaf(hv.z, wh1[4 * m + 2], ah1);
        bh1 = fmaf(hv.w, wh1[4 * m + 3], bh1);
      }

      // Refill slot with x row min(t+2, T-1); uniform cursor advance.
#pragma unroll
      for (int i = 0; i < 4; ++i)
        q[sl][i] = *reinterpret_cast<const float4*>(xp8 + 16 * i);
      xp8 += (t <= T_ - 4) ? xstride : (size_t)0;

      // Combine + 8-lane DPP butterfly per column.
      float r0 = (ax0 + ah0) + (bx0 + bh0);
      float r1 = (ax1 + ah1) + (bx1 + bh1);
      r0 = qp_add<0xB1>(r0);   r1 = qp_add<0xB1>(r1);   // xor1
      r0 = qp_add<0x4E>(r0);   r1 = qp_add<0x4E>(r1);   // xor2
      r0 = qp_add<0x141>(r0);  r1 = qp_add<0x141>(r1);  // xor4 (half-mirror)

      const float pre0 = r0 + bias0;
      const float pre1 = r1 + bias1;

      // tanh = sign * (1-e)/(1+e), e = exp(-2|pre|)
      const float aa0 = fabsf(pre0), aa1 = fabsf(pre1);
      const float e0 = __expf(-2.f * aa0), e1 = __expf(-2.f * aa1);
      const float s0 = (1.f - e0) * __builtin_amdgcn_rcpf(1.f + e0);
      const float s1 = (1.f - e1) * __builtin_amdgcn_rcpf(1.f + e1);
      const float hn0 = copysignf(s0, pre0);
      const float hn1 = copysignf(s1, pre1);

      if (kq == 0) {                     // publish h_{t+1} (ds_write_b64)
        *reinterpret_cast<float2*>(&hbuf[pr ^ 1][c0]) = make_float2(hn0, hn1);
      } else if (kq == 1) {              // H[t] -> global (stays in flight)
        *reinterpret_cast<float2*>(out + (size_t)t * ss + obase) =
            make_float2(hn0, hn1);
      }

      // LDS-only drain + raw barrier: vmcnt ops stay outstanding.
      asm volatile("s_waitcnt lgkmcnt(0)" ::: "memory");
      __builtin_amdgcn_s_barrier();
      __builtin_amdgcn_sched_barrier(0);
    }
  }
}

extern "C" void kernel_launch(void* const* d_in, const int* in_sizes, int n_in,
                              void* d_out, int out_size, void* d_ws, size_t ws_size,
                              hipStream_t stream) {
  const float* x  = (const float*)d_in[0];
  const float* h0 = (const float*)d_in[1];
  const float* Wx = (const float*)d_in[2];
  const float* bx = (const float*)d_in[3];
  const float* Wh = (const float*)d_in[4];
  const float* bh = (const float*)d_in[5];
  float* out = (float*)d_out;

  rnn_fused4<<<B_, 512, 0, stream>>>(x, h0, Wx, bx, Wh, bh, out);
}